// Round 6
// baseline (238.697 us; speedup 1.0000x reference)
//
#include <hip/hip_runtime.h>

typedef unsigned short u16;
typedef unsigned int u32;
typedef __attribute__((ext_vector_type(8))) short bf16x8;
typedef __attribute__((ext_vector_type(4))) short bf16x4;
typedef __attribute__((ext_vector_type(4))) float f32x4;

#define CSC 0.1803368801111244f  // 0.125 * log2(e), folded into K at projection

__device__ __forceinline__ u16 f2b(float f) {
  union { float f; u32 u; } c; c.f = f;
  return (u16)((c.u + 0x8000u) >> 16);
}

// pack 4 f32 -> 4 bf16 as uint2 (elem0 = low u16 of .x)
__device__ __forceinline__ uint2 pk4(f32x4 p) {
  union { float f; u32 u; } c0, c1, c2, c3;
  c0.f = p[0]; c1.f = p[1]; c2.f = p[2]; c3.f = p[3];
  u32 a = c0.u + 0x8000u, b = c1.u + 0x8000u;
  u32 c = c2.u + 0x8000u, d = c3.u + 0x8000u;
  uint2 r;
  r.x = __builtin_amdgcn_perm(b, a, 0x07060302u);
  r.y = __builtin_amdgcn_perm(d, c, 0x07060302u);
  return r;
}

__device__ __forceinline__ bf16x4 pk4v(f32x4 p) {
  union { uint2 u; bf16x4 v; } c;
  c.u = pk4(p);
  return c.v;
}

__device__ __forceinline__ void async16(const void* g, void* s) {
  __builtin_amdgcn_global_load_lds(
      (const __attribute__((address_space(1))) u32*)g,
      (__attribute__((address_space(3))) u32*)s, 16, 0, 0);
}

// ---------------- fused prep ----------------
// [0,4096) cvt x | [4096,10240) cvt ctx | [10240,10560) LDS-tiled W transpose |
// [10560,10562) mask -> mvalid floats + per-batch masked count
__global__ void prep(const float* __restrict__ x, const float* __restrict__ ctx,
                     const int* __restrict__ mask,
                     const float* __restrict__ Wq, const float* __restrict__ Wk,
                     const float* __restrict__ Wv, const float* __restrict__ Wo,
                     u16* __restrict__ Xb, u16* __restrict__ Cb,
                     float* __restrict__ mvalid, float* __restrict__ cnt,
                     u16* __restrict__ Wtq, u16* __restrict__ Wtkv, u16* __restrict__ Wto) {
  __shared__ u16 Tl[64 * 65];
  __shared__ int cred[4];
  const int bid = blockIdx.x, tid = threadIdx.x;
  if (bid < 10240) {
    const float* src; u16* dst; int i;
    if (bid < 4096) { i = (bid * 256 + tid) * 4; src = x; dst = Xb; }
    else { i = ((bid - 4096) * 256 + tid) * 4; src = ctx; dst = Cb; }
    float4 f = *(const float4*)&src[i];
    ushort4 o;
    o.x = f2b(f.x); o.y = f2b(f.y); o.z = f2b(f.z); o.w = f2b(f.w);
    *(ushort4*)&dst[i] = o;
  } else if (bid < 10560) {
    int t = bid - 10240;
    const float* W; u16* Wt; int Kd, tt;
    if (t < 64)       { W = Wq; Wt = Wtq;  Kd = 512; tt = t; }
    else if (t < 160) { W = Wk; Wt = Wtkv; Kd = 768; tt = t - 64; }
    else if (t < 256) { W = Wv; Wt = Wtkv + (size_t)512 * 768; Kd = 768; tt = t - 160; }
    else              { W = Wo; Wt = Wto;  Kd = 512; tt = t - 256; }
    const int k0 = (tt >> 3) * 64, n0 = (tt & 7) * 64;
    {
      const int r = tid >> 2, cg = (tid & 3) * 16;
#pragma unroll
      for (int i = 0; i < 4; i++) {
        float4 f = *(const float4*)&W[(size_t)(k0 + r) * 512 + n0 + cg + i * 4];
        Tl[r * 65 + cg + i * 4 + 0] = f2b(f.x);
        Tl[r * 65 + cg + i * 4 + 1] = f2b(f.y);
        Tl[r * 65 + cg + i * 4 + 2] = f2b(f.z);
        Tl[r * 65 + cg + i * 4 + 3] = f2b(f.w);
      }
    }
    __syncthreads();
    {
      const int n = tid >> 2, kg = (tid & 3) * 16;
      u16 buf[16];
#pragma unroll
      for (int i = 0; i < 16; i++) buf[i] = Tl[(kg + i) * 65 + n];
      u16* dst = &Wt[(size_t)(n0 + n) * Kd + k0 + kg];
      *(uint4*)dst = *(const uint4*)&buf[0];
      *(uint4*)(dst + 8) = *(const uint4*)&buf[8];
    }
  } else {
    const int b = bid - 10560;
    const int base = b * 4096;
    const int w = tid >> 6, lane = tid & 63;
    int zc = 0;
#pragma unroll
    for (int j = 0; j < 16; j++) {
      int idx = tid + j * 256;
      int mv = mask[base + idx];
      mvalid[base + idx] = mv ? 1.f : 0.f;
      zc += (mv == 0);
    }
#pragma unroll
    for (int d = 1; d < 64; d <<= 1) zc += __shfl_xor(zc, d);
    if (lane == 0) cred[w] = zc;
    __syncthreads();
    if (tid == 0) cnt[b] = (float)(cred[0] + cred[1] + cred[2] + cred[3]);
  }
}

// ---------------- fused QKV projection GEMM, 64x128 tiles ----------------
// grid (128, 12): y<4 -> Q-proj (A=Xb, K=512) cols y*128; y>=4 -> KV (A=Cb, K=768),
// cols (y-4)*128: <512 -> K' = K*CSC*mask row-major; >=512 -> V' = V*mask as V^T.
__global__ __launch_bounds__(256, 6)
void gemm_qkv(const u16* __restrict__ Xb, const u16* __restrict__ Cb,
              const u16* __restrict__ Wtq, const u16* __restrict__ Wtkv,
              const float* __restrict__ mvalid,
              u16* __restrict__ Qb, u16* __restrict__ Kb, u16* __restrict__ Vt) {
  __shared__ u16 As[64 * 64];
  __shared__ u16 Bs[128 * 64];
  const int tid = threadIdx.x;
  const int w = tid >> 6, lane = tid & 63, quad = lane >> 4, l16 = lane & 15;
  const int wr = w >> 1, wc = w & 1;
  const int y = blockIdx.y;
  const bool isQ = (y < 4);
  const u16* A  = isQ ? Xb : Cb;
  const u16* Bt = isQ ? Wtq : Wtkv;
  const int K   = isQ ? 512 : 768;
  const int n0  = isQ ? y * 128 : (y - 4) * 128;
  const size_t m0 = (size_t)blockIdx.x * 64;
  const u16* Ab = A + m0 * K;
  const u16* Bb = Bt + (size_t)n0 * K;

  const int cswz = (((lane & 7) ^ ((lane >> 3) & 7)) << 3);
  const int sw0 = ((quad ^ (l16 & 7)) << 3);
  const int sw1 = sw0 ^ 32;
  const int r8 = lane >> 3;

  f32x4 acc[2][4];
#pragma unroll
  for (int i = 0; i < 2; i++)
#pragma unroll
    for (int j = 0; j < 4; j++) acc[i][j] = (f32x4){0.f, 0.f, 0.f, 0.f};

  for (int k0 = 0; k0 < K; k0 += 64) {
    async16(Ab + (size_t)(w * 16 + r8) * K + k0 + cswz, &As[(w * 16) * 64]);
    async16(Ab + (size_t)(w * 16 + 8 + r8) * K + k0 + cswz, &As[(w * 16 + 8) * 64]);
#pragma unroll
    for (int t = 0; t < 4; t++)
      async16(Bb + (size_t)(w * 32 + t * 8 + r8) * K + k0 + cswz, &Bs[(w * 32 + t * 8) * 64]);
    __syncthreads();
#pragma unroll
    for (int ks = 0; ks < 2; ks++) {
      const int so = ks ? sw1 : sw0;
      bf16x8 af[2], bfr[4];
#pragma unroll
      for (int i = 0; i < 2; i++)
        af[i] = *(const bf16x8*)&As[(wr * 32 + i * 16 + l16) * 64 + so];
#pragma unroll
      for (int j = 0; j < 4; j++)
        bfr[j] = *(const bf16x8*)&Bs[(wc * 64 + j * 16 + l16) * 64 + so];
#pragma unroll
      for (int i = 0; i < 2; i++)
#pragma unroll
        for (int j = 0; j < 4; j++)
          acc[i][j] = __builtin_amdgcn_mfma_f32_16x16x32_bf16(af[i], bfr[j], acc[i][j], 0, 0, 0);
    }
    __syncthreads();
  }

  if (isQ) {
#pragma unroll
    for (int i = 0; i < 2; i++)
#pragma unroll
      for (int j = 0; j < 4; j++)
#pragma unroll
        for (int r = 0; r < 4; r++) {
          size_t row = m0 + wr * 32 + i * 16 + quad * 4 + r;
          Qb[row * 512 + n0 + wc * 64 + j * 16 + l16] = f2b(acc[i][j][r]);
        }
  } else if (n0 < 512) {
    // K' = K * CSC * mask (masked context rows -> exact 0)
#pragma unroll
    for (int i = 0; i < 2; i++) {
      size_t row0 = m0 + wr * 32 + i * 16 + quad * 4;
      f32x4 vm = *(const f32x4*)&mvalid[row0];
#pragma unroll
      for (int j = 0; j < 4; j++)
#pragma unroll
        for (int r = 0; r < 4; r++)
          Kb[(row0 + r) * 512 + n0 + wc * 64 + j * 16 + l16] = f2b(acc[i][j][r] * (vm[r] * CSC));
    }
  } else {
    // V' = V * mask, stored transposed: Vt[d][8192]
#pragma unroll
    for (int i = 0; i < 2; i++) {
      size_t row0 = m0 + wr * 32 + i * 16 + quad * 4;
      f32x4 vm = *(const f32x4*)&mvalid[row0];
#pragma unroll
      for (int j = 0; j < 4; j++) {
        int d = n0 - 512 + wc * 64 + j * 16 + l16;
        f32x4 v;
#pragma unroll
        for (int r = 0; r < 4; r++) v[r] = acc[i][j][r] * vm[r];
        *(uint2*)&Vt[(size_t)d * 8192 + row0] = pk4(v);
      }
    }
  }
}

// ---------------- O projection: 64x64 tiles, grid (128, 8) = 4 blocks/CU ----------------
__global__ __launch_bounds__(256, 4)
void gemm_o(const u16* __restrict__ A, const u16* __restrict__ Bt,
            const float* __restrict__ bias, float* __restrict__ Cf) {
  __shared__ u16 As[64 * 64];
  __shared__ u16 Bs[64 * 64];
  const int tid = threadIdx.x;
  const int w = tid >> 6, lane = tid & 63, quad = lane >> 4, l16 = lane & 15;
  const size_t m0 = (size_t)blockIdx.x * 64;
  const int n0 = blockIdx.y * 64;
  const u16* Ab = A + m0 * 512;
  const u16* Bb = Bt + (size_t)n0 * 512;

  const int cswz = (((lane & 7) ^ ((lane >> 3) & 7)) << 3);
  const int sw0 = ((quad ^ (l16 & 7)) << 3);
  const int sw1 = sw0 ^ 32;
  const int r8 = lane >> 3;

  f32x4 acc[4];
#pragma unroll
  for (int j = 0; j < 4; j++) acc[j] = (f32x4){0.f, 0.f, 0.f, 0.f};

  for (int k0 = 0; k0 < 512; k0 += 64) {
    async16(Ab + (size_t)(w * 16 + r8) * 512 + k0 + cswz, &As[(w * 16) * 64]);
    async16(Ab + (size_t)(w * 16 + 8 + r8) * 512 + k0 + cswz, &As[(w * 16 + 8) * 64]);
    async16(Bb + (size_t)(w * 16 + r8) * 512 + k0 + cswz, &Bs[(w * 16) * 64]);
    async16(Bb + (size_t)(w * 16 + 8 + r8) * 512 + k0 + cswz, &Bs[(w * 16 + 8) * 64]);
    __syncthreads();
#pragma unroll
    for (int ks = 0; ks < 2; ks++) {
      const int so = ks ? sw1 : sw0;
      bf16x8 af = *(const bf16x8*)&As[(w * 16 + l16) * 64 + so];
#pragma unroll
      for (int j = 0; j < 4; j++) {
        bf16x8 bfr = *(const bf16x8*)&Bs[(j * 16 + l16) * 64 + so];
        acc[j] = __builtin_amdgcn_mfma_f32_16x16x32_bf16(af, bfr, acc[j], 0, 0, 0);
      }
    }
    __syncthreads();
  }

#pragma unroll
  for (int j = 0; j < 4; j++)
#pragma unroll
    for (int r = 0; r < 4; r++) {
      size_t row = m0 + w * 16 + quad * 4 + r;
      int col = n0 + j * 16 + l16;
      Cf[row * 512 + col] = acc[j][r] + bias[col];
    }
}

// ---------------- flash attention: split-m across waves ----------------
// grid 1024 (l>>4 = qb, l&15 = hb; h = hb>>1, b = hb&1), block 256.
// Each block: 64 q rows. Wave w owns m-rows [w*16, w*16+16) of each 64-m tile:
// per wave-iter only 2 b128 K-frag reads + 4 b64 V-frag reads (frags amortize over
// 64 q held in registers). Partial O (over wave's m-slice) reduced across waves
// through the retired K/V LDS (f32) at the end.
__global__ __launch_bounds__(256, 3)
void attn_kernel(const u16* __restrict__ Q, const u16* __restrict__ Kg,
                 const u16* __restrict__ Vt, const float* __restrict__ cnt,
                 u16* __restrict__ AO) {
  __shared__ u16 KV[4][64 * 64];   // [0..1] K dbuf, [2..3] V dbuf; f32-aliased for O-reduce
  __shared__ float Lred[4][64];

  const int tid = threadIdx.x;
  const int w = tid >> 6, lane = tid & 63, quad = lane >> 4, l16 = lane & 15;
  const int l = blockIdx.x;
  const int qb = l >> 4, hb = l & 15, h = hb >> 1, b = hb & 1;
  const size_t qrow0 = (size_t)b * 4096 + (size_t)qb * 64;
  const size_t crow0 = (size_t)b * 4096;
  const int hcol = h * 64;
  const float cb = cnt[b];

  const int cswz = (((lane & 7) ^ ((lane >> 3) & 7)) << 3);
  const int sw0 = ((quad ^ (l16 & 7)) << 3);
  const int sw1 = sw0 ^ 32;
  const int r8 = lane >> 3;

  // Q B-fragments for all 4 q-subtiles (wave-redundant loads, L1/L2-served)
  bf16x8 qf[4][2];
#pragma unroll
  for (int qt = 0; qt < 4; qt++)
#pragma unroll
    for (int ks = 0; ks < 2; ks++)
      qf[qt][ks] = *(const bf16x8*)&Q[(qrow0 + qt * 16 + l16) * 512 + hcol + ks * 32 + quad * 8];

  // stage K/V tile 0
  async16(Kg + (crow0 + w * 16 + r8) * 512 + hcol + cswz, &KV[0][(w * 16) * 64]);
  async16(Kg + (crow0 + w * 16 + 8 + r8) * 512 + hcol + cswz, &KV[0][(w * 16 + 8) * 64]);
  async16(Vt + (size_t)(hcol + w * 16 + r8) * 8192 + crow0 + cswz, &KV[2][(w * 16) * 64]);
  async16(Vt + (size_t)(hcol + w * 16 + 8 + r8) * 8192 + crow0 + cswz, &KV[2][(w * 16 + 8) * 64]);
  __syncthreads();

  f32x4 Oacc[4][4];  // [qt][dt]: partial D[d][q] over wave's m-slice
#pragma unroll
  for (int qt = 0; qt < 4; qt++)
#pragma unroll
    for (int dt = 0; dt < 4; dt++) Oacc[qt][dt] = (f32x4){0.f, 0.f, 0.f, 0.f};
  float lsum[4] = {0.f, 0.f, 0.f, 0.f};

  const int krow = (w * 16 + l16) * 64;                       // wave's K-frag row base
  const int vbase = (((w * 2 + (quad >> 1)) ^ (l16 & 7)) << 3) + ((quad & 1) << 2);

  for (int mt = 0; mt < 64; mt++) {
    const int cur = mt & 1;

    if (mt < 63) {
      const size_t mn = (size_t)(mt + 1) * 64;
      async16(Kg + (crow0 + mn + w * 16 + r8) * 512 + hcol + cswz, &KV[cur ^ 1][(w * 16) * 64]);
      async16(Kg + (crow0 + mn + w * 16 + 8 + r8) * 512 + hcol + cswz, &KV[cur ^ 1][(w * 16 + 8) * 64]);
      async16(Vt + (size_t)(hcol + w * 16 + r8) * 8192 + crow0 + mn + cswz, &KV[2 + (cur ^ 1)][(w * 16) * 64]);
      async16(Vt + (size_t)(hcol + w * 16 + 8 + r8) * 8192 + crow0 + mn + cswz, &KV[2 + (cur ^ 1)][(w * 16 + 8) * 64]);
    }

    // S^T slice: A=K'[wave's 16 m][d], B=Q[64 q][d] -> D[m][q] per qt
    bf16x8 kf0 = *(const bf16x8*)&KV[cur][krow + sw0];
    bf16x8 kf1 = *(const bf16x8*)&KV[cur][krow + sw1];
    f32x4 sacc[4];
#pragma unroll
    for (int qt = 0; qt < 4; qt++) sacc[qt] = (f32x4){0.f, 0.f, 0.f, 0.f};
#pragma unroll
    for (int qt = 0; qt < 4; qt++)
      sacc[qt] = __builtin_amdgcn_mfma_f32_16x16x32_bf16(kf0, qf[qt][0], sacc[qt], 0, 0, 0);
#pragma unroll
    for (int qt = 0; qt < 4; qt++)
      sacc[qt] = __builtin_amdgcn_mfma_f32_16x16x32_bf16(kf1, qf[qt][1], sacc[qt], 0, 0, 0);

    // p = exp2(s) (K pre-scaled+masked); masked rows -> p=1, fixed via cnt
    bf16x4 pf[4];
#pragma unroll
    for (int qt = 0; qt < 4; qt++) {
      f32x4 p;
#pragma unroll
      for (int r = 0; r < 4; r++) {
        p[r] = __builtin_amdgcn_exp2f(sacc[qt][r]);
        lsum[qt] += p[r];
      }
      pf[qt] = pk4v(p);
    }

    // O^T partial += mfma_16x16x16(A=V'^T[d][wave's m-chunk], B=P)
#pragma unroll
    for (int dt = 0; dt < 4; dt++) {
      bf16x4 va = *(const bf16x4*)&KV[2 + cur][(dt * 16 + l16) * 64 + vbase];
#pragma unroll
      for (int qt = 0; qt < 4; qt++)
        Oacc[qt][dt] = __builtin_amdgcn_mfma_f32_16x16x16bf16_1k(va, pf[qt], Oacc[qt][dt], 0, 0, 0);
    }
    __syncthreads();
  }

  // ---- cross-wave reduction (KV LDS retired; alias as f32) ----
  float* Ored = (float*)&KV[0][0];  // 2 x 64x64 f32 regions

  // per-q denominators: reduce lsum across quads, publish per wave
#pragma unroll
  for (int qt = 0; qt < 4; qt++) {
    lsum[qt] += __shfl_xor(lsum[qt], 16);
    lsum[qt] += __shfl_xor(lsum[qt], 32);
  }
  if (lane < 16) {
#pragma unroll
    for (int qt = 0; qt < 4; qt++) Lred[w][qt * 16 + l16] = lsum[qt];
  }

  if (w >= 2) {
    float* dst = Ored + (w - 2) * 4096;
#pragma unroll
    for (int qt = 0; qt < 4; qt++)
#pragma unroll
      for (int dt = 0; dt < 4; dt++)
#pragma unroll
        for (int r = 0; r < 4; r++)
          dst[(dt * 16 + quad * 4 + r) * 64 + qt * 16 + l16] = Oacc[qt][dt][r];
  }
  __syncthreads();
  if (w < 2) {
    const float* src = Ored + w * 4096;
#pragma unroll
    for (int qt = 0; qt < 4; qt++)
#pragma unroll
      for (int dt = 0; dt < 4; dt++)
#pragma unroll
        for (int r = 0; r < 4; r++)
          Oacc[qt][dt][r] += src[(dt * 16 + quad * 4 + r) * 64 + qt * 16 + l16];
  }
  __syncthreads();
  if (w == 1) {
#pragma unroll
    for (int qt = 0; qt < 4; qt++)
#pragma unroll
      for (int dt = 0; dt < 4; dt++)
#pragma unroll
        for (int r = 0; r < 4; r++)
          Ored[(dt * 16 + quad * 4 + r) * 64 + qt * 16 + l16] = Oacc[qt][dt][r];
  }
  __syncthreads();
  if (w == 0) {
    float inv[4];
#pragma unroll
    for (int qt = 0; qt < 4; qt++) {
      int q = qt * 16 + l16;
      inv[qt] = 1.0f / (Lred[0][q] + Lred[1][q] + Lred[2][q] + Lred[3][q] - cb);
    }
#pragma unroll
    for (int qt = 0; qt < 4; qt++)
#pragma unroll
      for (int dt = 0; dt < 4; dt++) {
        f32x4 o;
#pragma unroll
        for (int r = 0; r < 4; r++)
          o[r] = (Oacc[qt][dt][r] + Ored[(dt * 16 + quad * 4 + r) * 64 + qt * 16 + l16]) * inv[qt];
        *(uint2*)&AO[(qrow0 + qt * 16 + l16) * 512 + hcol + dt * 16 + quad * 4] = pk4(o);
      }
  }
}

// ---------------- host ----------------

extern "C" void kernel_launch(void* const* d_in, const int* in_sizes, int n_in,
                              void* d_out, int out_size, void* d_ws, size_t ws_size,
                              hipStream_t stream) {
  const float* x   = (const float*)d_in[0];
  const float* ctx = (const float*)d_in[1];
  const int*  mask = (const int*)d_in[2];
  const float* Wq  = (const float*)d_in[3];
  const float* Wk  = (const float*)d_in[4];
  const float* Wv  = (const float*)d_in[5];
  const float* Wo  = (const float*)d_in[6];
  const float* bo  = (const float*)d_in[7];
  float* out = (float*)d_out;

  char* p = (char*)d_ws;
  u16* Xb   = (u16*)p; p += (size_t)8192 * 512 * 2;
  u16* Cb   = (u16*)p; p += (size_t)8192 * 768 * 2;
  u16* Wtq  = (u16*)p; p += (size_t)512 * 512 * 2;
  u16* Wtkv = (u16*)p; p += (size_t)1024 * 768 * 2;
  u16* Wto  = (u16*)p; p += (size_t)512 * 512 * 2;
  u16* Qb   = (u16*)p; p += (size_t)8192 * 512 * 2;
  u16* Kb   = (u16*)p; p += (size_t)8192 * 512 * 2;
  u16* Vtg  = (u16*)p; p += (size_t)512 * 8192 * 2;
  u16* AOb  = (u16*)p; p += (size_t)8192 * 512 * 2;
  float* mvalid = (float*)p; p += (size_t)8192 * 4;
  float* cnt    = (float*)p; p += 2 * 4;

  prep<<<10562, 256, 0, stream>>>(x, ctx, mask, Wq, Wk, Wv, Wo,
                                  Xb, Cb, mvalid, cnt, Wtq, Wtkv, Wto);
  gemm_qkv<<<dim3(128, 12), 256, 0, stream>>>(Xb, Cb, Wtq, Wtkv, mvalid, Qb, Kb, Vtg);
  attn_kernel<<<1024, 256, 0, stream>>>(Qb, Kb, Vtg, cnt, AOb);
  gemm_o<<<dim3(128, 8), 256, 0, stream>>>(AOb, Wto, bo, out);
}